// Round 3
// baseline (696.127 us; speedup 1.0000x reference)
//
#include <hip/hip_runtime.h>

#define D_MODEL 256
#define NSEQ    8192
#define PV_GROUPS 8

typedef _Float16 half8 __attribute__((ext_vector_type(8)));
typedef _Float16 half4 __attribute__((ext_vector_type(4)));
typedef float    f32x4 __attribute__((ext_vector_type(4)));

typedef __attribute__((address_space(1))) const void* gptr_t;
typedef __attribute__((address_space(3))) void*       lptr_t;

__device__ __forceinline__ half8 cvt8(f32x4 a, f32x4 b) {
  half8 h;
  h[0]=(_Float16)a[0]; h[1]=(_Float16)a[1]; h[2]=(_Float16)a[2]; h[3]=(_Float16)a[3];
  h[4]=(_Float16)b[0]; h[5]=(_Float16)b[1]; h[6]=(_Float16)b[2]; h[7]=(_Float16)b[3];
  return h;
}

__device__ __forceinline__ half8 load8_f32(const float* p) {
  f32x4 a = *(const f32x4*)p;
  f32x4 b = *(const f32x4*)(p + 4);
  return cvt8(a, b);
}

// ---------------------------------------------------------------------------
// P16F fragment-tiled layout for unnormalized p (the key enabler):
//   tile (tq = q>>4, tj = j>>5), 1KB each, linear index tq*256 + tj.
//   within tile: half index = L*8 + e, L = ((j>>3)&3)*16 + (q&15), e = j&7.
// A wave reading half8 at [tile_base + lane*8] holds exactly the
// mfma_16x16x32_f16 A-fragment: A[m = lane&15 = q][k = (lane>>4)*8 + e = j].
// => pv stages one tile per wave with a single global_load_lds (linear LDS,
//    conflict-free b128 reads), no transpose, no swizzle.
// ---------------------------------------------------------------------------

// ---------------------------------------------------------------------------
// k1: QKV = x @ W^T. 1-wave blocks, grid (128,12) = 1536 resident waves.
// ---------------------------------------------------------------------------
__global__ __launch_bounds__(64, 3) void qkv_kernel(
    const float* __restrict__ x, const float* __restrict__ Wq,
    const float* __restrict__ Wk, const float* __restrict__ Wv,
    _Float16* __restrict__ QK16, _Float16* __restrict__ VT)
{
  const int lane = threadIdx.x & 63;
  const int c    = lane & 15;
  const int quad = lane >> 4;
  const int M0   = blockIdx.x * 64;
  const int Nblk = blockIdx.y * 64;                      // 0..704
  const int widx = Nblk >> 8;                            // 0=Q,1=K,2=V
  const int nloc = Nblk & 255;
  const float* W = (widx == 0) ? Wq : (widx == 1 ? Wk : Wv);

  f32x4 acc[4][4] = {};
  for (int k0 = 0; k0 < D_MODEL; k0 += 32) {
    half8 af[4], bf[4];
#pragma unroll
    for (int mt = 0; mt < 4; ++mt)
      af[mt] = load8_f32(&x[(size_t)(M0 + mt*16 + c) * D_MODEL + k0 + quad*8]);
#pragma unroll
    for (int nt = 0; nt < 4; ++nt)
      bf[nt] = load8_f32(&W[(size_t)(nloc + nt*16 + c) * D_MODEL + k0 + quad*8]);
#pragma unroll
    for (int mt = 0; mt < 4; ++mt)
#pragma unroll
      for (int nt = 0; nt < 4; ++nt)
        acc[mt][nt] = __builtin_amdgcn_mfma_f32_16x16x32_f16(af[mt], bf[nt], acc[mt][nt], 0, 0, 0);
  }

  if (widx < 2) {
#pragma unroll
    for (int mt = 0; mt < 4; ++mt)
#pragma unroll
      for (int nt = 0; nt < 4; ++nt) {
        const int col  = widx * 256 + nloc + nt*16 + c;
        const int row0 = M0 + mt*16 + quad*4;
#pragma unroll
        for (int r = 0; r < 4; ++r)
          QK16[(size_t)(row0 + r) * 512 + col] = (_Float16)acc[mt][nt][r];
      }
  } else {
#pragma unroll
    for (int mt = 0; mt < 4; ++mt)
#pragma unroll
      for (int nt = 0; nt < 4; ++nt) {
        const int d  = nloc + nt*16 + c;
        const int m0 = M0 + mt*16 + quad*4;
        half4 h;
        h[0]=(_Float16)acc[mt][nt][0]; h[1]=(_Float16)acc[mt][nt][1];
        h[2]=(_Float16)acc[mt][nt][2]; h[3]=(_Float16)acc[mt][nt][3];
        *(half4*)&VT[(size_t)d * NSEQ + m0] = h;
      }
  }
}

// ---------------------------------------------------------------------------
// k2: p = exp(Q@K^T / 16), row sums into lsum.
// P16=true:  write p16 in P16F fragment-tiled layout (see above).
// P16=false: legacy row-major f32 into attn (fallback path).
// ---------------------------------------------------------------------------
template<bool P16>
__global__ __launch_bounds__(256, 3) void score_kernel(
    const _Float16* __restrict__ QK16, void* __restrict__ Pout,
    float* __restrict__ lsum)
{
  const int tid  = threadIdx.x;
  const int lane = tid & 63;
  const int wave = tid >> 6;
  const int c    = lane & 15;
  const int quad = lane >> 4;
  const int M0   = blockIdx.x * 128 + (wave >> 1) * 64;
  const int N0   = blockIdx.y * 128 + (wave & 1) * 64;

  f32x4 acc[4][4] = {};
  half8 afA[4], bfA[4], afB[4], bfB[4];

  auto ld = [&](half8 (&af)[4], half8 (&bf)[4], int k0) {
#pragma unroll
    for (int mt = 0; mt < 4; ++mt)
      af[mt] = *(const half8*)&QK16[(size_t)(M0 + mt*16 + c) * 512 + k0 + quad*8];
#pragma unroll
    for (int nt = 0; nt < 4; ++nt)
      bf[nt] = *(const half8*)&QK16[(size_t)(N0 + nt*16 + c) * 512 + 256 + k0 + quad*8];
  };
  auto mm = [&](half8 (&af)[4], half8 (&bf)[4]) {
#pragma unroll
    for (int mt = 0; mt < 4; ++mt)
#pragma unroll
      for (int nt = 0; nt < 4; ++nt)
        acc[mt][nt] = __builtin_amdgcn_mfma_f32_16x16x32_f16(af[mt], bf[nt], acc[mt][nt], 0, 0, 0);
  };

  ld(afA, bfA, 0);
#pragma unroll
  for (int k0 = 0; k0 < 256; k0 += 64) {
    ld(afB, bfB, k0 + 32);
    mm(afA, bfA);
    if (k0 + 64 < 256) ld(afA, bfA, k0 + 64);
    mm(afB, bfB);
  }

  float psum[4][4] = {};   // [mt][r] partial row sums
#pragma unroll
  for (int mt = 0; mt < 4; ++mt) {
    const size_t tq = (size_t)((M0 + mt*16) >> 4);
#pragma unroll
    for (int nt = 0; nt < 4; ++nt) {
      // P16F base for this (mt,nt) fragment block, this lane:
      const size_t tj   = (size_t)((N0 >> 5) + (nt >> 1));
      const size_t base = (tq * 256 + tj) * 512
                        + (size_t)(((nt*2 + (c>>3)) & 3) * 128 + quad*32 + (c & 7));
#pragma unroll
      for (int r = 0; r < 4; ++r) {
        const float p = __expf(acc[mt][nt][r] * 0.0625f);
        psum[mt][r] += p;
        if constexpr (P16) {
          ((_Float16*)Pout)[base + r*8] = (_Float16)p;
        } else {
          const size_t idx = (size_t)(M0 + mt*16 + quad*4 + r) * NSEQ + N0 + nt*16 + c;
          ((float*)Pout)[idx] = p;
        }
      }
    }
  }

#pragma unroll
  for (int mt = 0; mt < 4; ++mt)
#pragma unroll
    for (int r = 0; r < 4; ++r) {
      float v = psum[mt][r];
      v += __shfl_xor(v, 1);
      v += __shfl_xor(v, 2);
      v += __shfl_xor(v, 4);
      v += __shfl_xor(v, 8);
      if (c == 0) atomicAdd(&lsum[M0 + mt*16 + quad*4 + r], v);
    }
}

// ---------------------------------------------------------------------------
// k3 (P16F path): attn = p/lsum written once (from A-frag regs);
//                 cntx += (p@V)/lsum.
// Double-buffered async LDS staging via global_load_lds (m97 structure):
// each wave stages its 1KB P16F tile per 64-j chunk fire-and-forget (no
// VGPR cost), barrier drains vmcnt, A-frags are conflict-free ds_read_b128.
// This removes the register-pipeline the compiler kept collapsing (R1/R2:
// VGPR=84 = acc+ONE frag set => serialized; VALUBusy 4%).
// ---------------------------------------------------------------------------
__global__ __launch_bounds__(256) void pv_kernel_p16(
    const _Float16* __restrict__ P16F, float* __restrict__ attn,
    const float* __restrict__ lsum, const _Float16* __restrict__ VT,
    float* __restrict__ cntx)
{
  __shared__ alignas(16) _Float16 As[2 * 4 * 512];   // [buf][tile(mt*2+ks)][512]
  __shared__ float linv[32];
  const int tid  = threadIdx.x;
  const int lane = tid & 63;
  const int wave = tid >> 6;
  const int c    = lane & 15;
  const int quad = lane >> 4;
  const int M0   = blockIdx.x * 32;
  const int jb   = blockIdx.y * (NSEQ / PV_GROUPS);
  const int je   = jb + NSEQ / PV_GROUPS;
  const int D0   = wave * 64;
  const int wmt  = wave >> 1;           // attn-write sub-fragment owned by wave
  const int wks  = wave & 1;

  if (tid < 32) linv[tid] = 1.0f / lsum[M0 + tid];

  // this wave's staging tile: (tq = M0/16 + wmt, tj = j0/32 + wks)
  const size_t tq = (size_t)((M0 >> 4) + wmt);

  // prologue: stage chunk 0 into buf 0
  {
    const _Float16* src = P16F + (tq * 256 + (size_t)((jb >> 5) + wks)) * 512 + lane * 8;
    __builtin_amdgcn_global_load_lds((gptr_t)src, (lptr_t)&As[wave * 512], 16, 0, 0);
  }
  __syncthreads();                      // stage 0 complete + linv visible

  const float sw = linv[wmt * 16 + c];  // loop-invariant attn scale for this lane

  f32x4 acc[2][4] = {};
  int buf = 0;
  for (int j0 = jb; j0 < je; j0 += 64) {
    if (j0 + 64 < je) {
      const _Float16* src = P16F + (tq * 256 + (size_t)(((j0 + 64) >> 5) + wks)) * 512 + lane * 8;
      __builtin_amdgcn_global_load_lds((gptr_t)src,
          (lptr_t)&As[(buf ^ 1) * 2048 + wave * 512], 16, 0, 0);
    }

    // A-frags: conflict-free b128, all 4 tiles shared by all waves
    half8 af[2][2];
#pragma unroll
    for (int mt = 0; mt < 2; ++mt)
#pragma unroll
      for (int ks = 0; ks < 2; ++ks)
        af[mt][ks] = *(const half8*)&As[buf * 2048 + (mt*2 + ks) * 512 + lane * 8];

    // B-frags: VT rows (L2-hot, 4MB total)
    half8 bf[4][2];
#pragma unroll
    for (int ks = 0; ks < 2; ++ks)
#pragma unroll
      for (int nt = 0; nt < 4; ++nt)
        bf[nt][ks] = *(const half8*)&VT[(size_t)(D0 + nt*16 + c) * NSEQ + j0 + ks*32 + quad*8];

    // attn write: wave w owns sub-frag (wmt, wks) => every element once
    {
      const half8 v = af[wmt][wks];
      f32x4 w0, w1;
#pragma unroll
      for (int r = 0; r < 4; ++r) {
        w0[r] = (float)v[r]     * sw;
        w1[r] = (float)v[r + 4] * sw;
      }
      float* ar = attn + (size_t)(M0 + wmt*16 + c) * NSEQ + j0 + wks*32 + quad*8;
      *(f32x4*)ar       = w0;
      *(f32x4*)(ar + 4) = w1;
    }

    // PV MFMA (unnormalized accumulate)
#pragma unroll
    for (int ks = 0; ks < 2; ++ks)
#pragma unroll
      for (int mt = 0; mt < 2; ++mt)
#pragma unroll
        for (int nt = 0; nt < 4; ++nt)
          acc[mt][nt] = __builtin_amdgcn_mfma_f32_16x16x32_f16(af[mt][ks], bf[nt][ks], acc[mt][nt], 0, 0, 0);

    __syncthreads();                    // drains staging vmcnt; protects buf reuse
    buf ^= 1;
  }

  // epilogue: scale by 1/lsum, accumulate into cntx
#pragma unroll
  for (int mt = 0; mt < 2; ++mt)
#pragma unroll
    for (int r = 0; r < 4; ++r) {
      const float s = linv[mt*16 + quad*4 + r];
#pragma unroll
      for (int nt = 0; nt < 4; ++nt)
        atomicAdd(&cntx[(size_t)(M0 + mt*16 + quad*4 + r) * D_MODEL + D0 + nt*16 + c],
                  acc[mt][nt][r] * s);
    }
}

// ---------------------------------------------------------------------------
// k3 fallback (small ws): in-place f32 normalize + PV, unchanged semantics.
// ---------------------------------------------------------------------------
__global__ __launch_bounds__(256) void pv_kernel_f32(
    const float* __restrict__ Pin, float* __restrict__ attn,
    const float* __restrict__ lsum, const _Float16* __restrict__ VT,
    float* __restrict__ cntx)
{
  __shared__ float linv[32];
  const int tid  = threadIdx.x;
  const int lane = tid & 63;
  const int wave = tid >> 6;
  const int c    = lane & 15;
  const int quad = lane >> 4;
  const int M0   = blockIdx.x * 32;
  const int jb   = blockIdx.y * (NSEQ / PV_GROUPS);
  const int je   = jb + NSEQ / PV_GROUPS;
  const int D0   = wave * 64;
  const int nr   = tid >> 3;
  const int ncol = (tid & 7) * 8;

  if (tid < 32) linv[tid] = 1.0f / lsum[M0 + tid];
  __syncthreads();
  const float nscale = linv[nr];

  f32x4 acc[2][4] = {};
  for (int j0 = jb; j0 < je; j0 += 64) {
    const float* pr = Pin + (size_t)(M0 + nr) * NSEQ + j0 + ncol;
    f32x4 np0 = *(const f32x4*)pr;
    f32x4 np1 = *(const f32x4*)(pr + 4);

    half8 af[2][2], bf[4][2];
#pragma unroll
    for (int h = 0; h < 2; ++h) {
#pragma unroll
      for (int mt = 0; mt < 2; ++mt) {
        const float* pa = Pin + (size_t)(M0 + mt*16 + c) * NSEQ + j0 + h*32 + quad*8;
        af[mt][h] = cvt8(*(const f32x4*)pa, *(const f32x4*)(pa + 4));
      }
#pragma unroll
      for (int nt = 0; nt < 4; ++nt)
        bf[nt][h] = *(const half8*)&VT[(size_t)(D0 + nt*16 + c) * NSEQ + j0 + h*32 + quad*8];
    }

    __syncthreads();   // all reads of this tile before in-place writes

    float* ar = attn + (size_t)(M0 + nr) * NSEQ + j0 + ncol;
    *(f32x4*)ar       = np0 * nscale;
    *(f32x4*)(ar + 4) = np1 * nscale;

#pragma unroll
    for (int h = 0; h < 2; ++h)
#pragma unroll
      for (int mt = 0; mt < 2; ++mt)
#pragma unroll
        for (int nt = 0; nt < 4; ++nt)
          acc[mt][nt] = __builtin_amdgcn_mfma_f32_16x16x32_f16(af[mt][h], bf[nt][h], acc[mt][nt], 0, 0, 0);
  }

#pragma unroll
  for (int mt = 0; mt < 2; ++mt)
#pragma unroll
    for (int r = 0; r < 4; ++r) {
      const float s = linv[mt*16 + quad*4 + r];
#pragma unroll
      for (int nt = 0; nt < 4; ++nt)
        atomicAdd(&cntx[(size_t)(M0 + mt*16 + quad*4 + r) * D_MODEL + D0 + nt*16 + c],
                  acc[mt][nt][r] * s);
    }
}

// ---------------------------------------------------------------------------
extern "C" void kernel_launch(void* const* d_in, const int* in_sizes, int n_in,
                              void* d_out, int out_size, void* d_ws, size_t ws_size,
                              hipStream_t stream)
{
  const float* x  = (const float*)d_in[0];
  const float* Wq = (const float*)d_in[1];
  const float* Wk = (const float*)d_in[2];
  const float* Wv = (const float*)d_in[3];

  float* cntx = (float*)d_out;                         // [8192 x 256]
  float* attn = cntx + (size_t)NSEQ * D_MODEL;         // [8192 x 8192]

  // ws layout: QK16 (8MB) | VT (4MB) | lsum (32KB) | P16F (128MB, if room)
  _Float16* QK16 = (_Float16*)d_ws;
  _Float16* VT   = QK16 + (size_t)NSEQ * 512;
  float*    lsum = (float*)(VT + (size_t)D_MODEL * NSEQ);
  _Float16* P16F = (_Float16*)(lsum + NSEQ);

  const size_t base_bytes = (size_t)NSEQ*512*2 + (size_t)D_MODEL*NSEQ*2 + (size_t)NSEQ*4;
  const bool big_ws = ws_size >= base_bytes + (size_t)NSEQ * NSEQ * 2;

  hipMemsetAsync(cntx, 0, sizeof(float) * (size_t)NSEQ * D_MODEL, stream);
  hipMemsetAsync(lsum, 0, sizeof(float) * NSEQ, stream);

  qkv_kernel<<<dim3(128, 12), 64, 0, stream>>>(x, Wq, Wk, Wv, QK16, VT);

  if (big_ws) {
    score_kernel<true><<<dim3(64, 64), 256, 0, stream>>>(QK16, (void*)P16F, lsum);
    pv_kernel_p16<<<dim3(NSEQ/32, PV_GROUPS), 256, 0, stream>>>(P16F, attn, lsum, VT, cntx);
  } else {
    score_kernel<false><<<dim3(64, 64), 256, 0, stream>>>(QK16, (void*)attn, lsum);
    pv_kernel_f32<<<dim3(NSEQ/32, PV_GROUPS), 256, 0, stream>>>(attn, attn, lsum, VT, cntx);
  }
}

// Round 5
// 615.967 us; speedup vs baseline: 1.1301x; 1.1301x over previous
//
#include <hip/hip_runtime.h>

#define D_MODEL 256
#define NSEQ    8192
#define PV_GROUPS 8

typedef _Float16 half8 __attribute__((ext_vector_type(8)));
typedef _Float16 half4 __attribute__((ext_vector_type(4)));
typedef float    f32x4 __attribute__((ext_vector_type(4)));

typedef __attribute__((address_space(1))) const void* gptr_t;
typedef __attribute__((address_space(3))) void*       lptr_t;

__device__ __forceinline__ half8 cvt8(f32x4 a, f32x4 b) {
  half8 h;
  h[0]=(_Float16)a[0]; h[1]=(_Float16)a[1]; h[2]=(_Float16)a[2]; h[3]=(_Float16)a[3];
  h[4]=(_Float16)b[0]; h[5]=(_Float16)b[1]; h[6]=(_Float16)b[2]; h[7]=(_Float16)b[3];
  return h;
}

__device__ __forceinline__ half8 load8_f32(const float* p) {
  f32x4 a = *(const f32x4*)p;
  f32x4 b = *(const f32x4*)(p + 4);
  return cvt8(a, b);
}

// ---------------------------------------------------------------------------
// P16F fragment-tiled layout for unnormalized p:
//   tile (tq = q>>4, tj = j>>5), 1KB each, linear index tq*256 + tj.
//   within tile: half index = L*8 + e, L = ((j>>3)&3)*16 + (q&15), e = j&7.
// A wave reading half8 at [tile_base + lane*8] holds exactly the
// mfma_16x16x32_f16 A-fragment. Row-contiguous access (row q, j-octet g) is
// the contiguous half8 at [((g&3)*16 + (q&15))*8] of tile (q>>4, g>>2).
// ---------------------------------------------------------------------------

// ---------------------------------------------------------------------------
// k1: QKV = x @ W^T. 1-wave blocks, grid (128,12) = 1536 resident waves.
// ---------------------------------------------------------------------------
__global__ __launch_bounds__(64, 3) void qkv_kernel(
    const float* __restrict__ x, const float* __restrict__ Wq,
    const float* __restrict__ Wk, const float* __restrict__ Wv,
    _Float16* __restrict__ QK16, _Float16* __restrict__ VT)
{
  const int lane = threadIdx.x & 63;
  const int c    = lane & 15;
  const int quad = lane >> 4;
  const int M0   = blockIdx.x * 64;
  const int Nblk = blockIdx.y * 64;                      // 0..704
  const int widx = Nblk >> 8;                            // 0=Q,1=K,2=V
  const int nloc = Nblk & 255;
  const float* W = (widx == 0) ? Wq : (widx == 1 ? Wk : Wv);

  f32x4 acc[4][4] = {};
  for (int k0 = 0; k0 < D_MODEL; k0 += 32) {
    half8 af[4], bf[4];
#pragma unroll
    for (int mt = 0; mt < 4; ++mt)
      af[mt] = load8_f32(&x[(size_t)(M0 + mt*16 + c) * D_MODEL + k0 + quad*8]);
#pragma unroll
    for (int nt = 0; nt < 4; ++nt)
      bf[nt] = load8_f32(&W[(size_t)(nloc + nt*16 + c) * D_MODEL + k0 + quad*8]);
#pragma unroll
    for (int mt = 0; mt < 4; ++mt)
#pragma unroll
      for (int nt = 0; nt < 4; ++nt)
        acc[mt][nt] = __builtin_amdgcn_mfma_f32_16x16x32_f16(af[mt], bf[nt], acc[mt][nt], 0, 0, 0);
  }

  if (widx < 2) {
#pragma unroll
    for (int mt = 0; mt < 4; ++mt)
#pragma unroll
      for (int nt = 0; nt < 4; ++nt) {
        const int col  = widx * 256 + nloc + nt*16 + c;
        const int row0 = M0 + mt*16 + quad*4;
#pragma unroll
        for (int r = 0; r < 4; ++r)
          QK16[(size_t)(row0 + r) * 512 + col] = (_Float16)acc[mt][nt][r];
      }
  } else {
#pragma unroll
    for (int mt = 0; mt < 4; ++mt)
#pragma unroll
      for (int nt = 0; nt < 4; ++nt) {
        const int d  = nloc + nt*16 + c;
        const int m0 = M0 + mt*16 + quad*4;
        half4 h;
        h[0]=(_Float16)acc[mt][nt][0]; h[1]=(_Float16)acc[mt][nt][1];
        h[2]=(_Float16)acc[mt][nt][2]; h[3]=(_Float16)acc[mt][nt][3];
        *(half4*)&VT[(size_t)d * NSEQ + m0] = h;
      }
  }
}

// ---------------------------------------------------------------------------
// k2: p = exp(Q@K^T / 16), row sums into lsum.
// P16=true:  write p16 in P16F fragment-tiled layout (sector-clean: each 1KB
//            tile written entirely by one wave).
// P16=false: legacy row-major f32 into attn (fallback path).
// ---------------------------------------------------------------------------
template<bool P16>
__global__ __launch_bounds__(256, 3) void score_kernel(
    const _Float16* __restrict__ QK16, void* __restrict__ Pout,
    float* __restrict__ lsum)
{
  const int tid  = threadIdx.x;
  const int lane = tid & 63;
  const int wave = tid >> 6;
  const int c    = lane & 15;
  const int quad = lane >> 4;
  const int M0   = blockIdx.x * 128 + (wave >> 1) * 64;
  const int N0   = blockIdx.y * 128 + (wave & 1) * 64;

  f32x4 acc[4][4] = {};
  half8 afA[4], bfA[4], afB[4], bfB[4];

  auto ld = [&](half8 (&af)[4], half8 (&bf)[4], int k0) {
#pragma unroll
    for (int mt = 0; mt < 4; ++mt)
      af[mt] = *(const half8*)&QK16[(size_t)(M0 + mt*16 + c) * 512 + k0 + quad*8];
#pragma unroll
    for (int nt = 0; nt < 4; ++nt)
      bf[nt] = *(const half8*)&QK16[(size_t)(N0 + nt*16 + c) * 512 + 256 + k0 + quad*8];
  };
  auto mm = [&](half8 (&af)[4], half8 (&bf)[4]) {
#pragma unroll
    for (int mt = 0; mt < 4; ++mt)
#pragma unroll
      for (int nt = 0; nt < 4; ++nt)
        acc[mt][nt] = __builtin_amdgcn_mfma_f32_16x16x32_f16(af[mt], bf[nt], acc[mt][nt], 0, 0, 0);
  };

  ld(afA, bfA, 0);
#pragma unroll
  for (int k0 = 0; k0 < 256; k0 += 64) {
    ld(afB, bfB, k0 + 32);
    mm(afA, bfA);
    if (k0 + 64 < 256) ld(afA, bfA, k0 + 64);
    mm(afB, bfB);
  }

  float psum[4][4] = {};   // [mt][r] partial row sums
#pragma unroll
  for (int mt = 0; mt < 4; ++mt) {
    const size_t tq = (size_t)((M0 + mt*16) >> 4);
#pragma unroll
    for (int nt = 0; nt < 4; ++nt) {
      // P16F base for this (mt,nt) fragment block, this lane:
      const size_t tj   = (size_t)((N0 >> 5) + (nt >> 1));
      const size_t base = (tq * 256 + tj) * 512
                        + (size_t)(((nt*2 + (c>>3)) & 3) * 128 + quad*32 + (c & 7));
#pragma unroll
      for (int r = 0; r < 4; ++r) {
        const float p = __expf(acc[mt][nt][r] * 0.0625f);
        psum[mt][r] += p;
        if constexpr (P16) {
          ((_Float16*)Pout)[base + r*8] = (_Float16)p;
        } else {
          const size_t idx = (size_t)(M0 + mt*16 + quad*4 + r) * NSEQ + N0 + nt*16 + c;
          ((float*)Pout)[idx] = p;
        }
      }
    }
  }

#pragma unroll
  for (int mt = 0; mt < 4; ++mt)
#pragma unroll
    for (int r = 0; r < 4; ++r) {
      float v = psum[mt][r];
      v += __shfl_xor(v, 1);
      v += __shfl_xor(v, 2);
      v += __shfl_xor(v, 4);
      v += __shfl_xor(v, 8);
      if (c == 0) atomicAdd(&lsum[M0 + mt*16 + quad*4 + r], v);
    }
}

// ---------------------------------------------------------------------------
// k3 (P16F path): attn = p/lsum written once; cntx += (p@V)/lsum.
// Async LDS double-buffer staging via global_load_lds (R3 structure — gave
// occupancy 45%, BW 2.5 TB/s). CHANGED vs R3: the attn write no longer comes
// from the A-frag registers (lane→row=c, 4x16B scattered per row per instr →
// half-sector writes completed by a DIFFERENT wave → HBM sector written
// twice → WRITE_SIZE 606MB). Instead re-read the staged LDS tile in
// row-contiguous order (thread=(q=tid>>3, g=tid&7) → contiguous half8) and
// store 256B-contiguous per row per wave in adjacent instrs → full sectors.
// ---------------------------------------------------------------------------
__global__ __launch_bounds__(256) void pv_kernel_p16(
    const _Float16* __restrict__ P16F, float* __restrict__ attn,
    const float* __restrict__ lsum, const _Float16* __restrict__ VT,
    float* __restrict__ cntx)
{
  __shared__ alignas(16) _Float16 As[2 * 4 * 512];   // [buf][tile(mt*2+ks)][512]
  __shared__ float linv[32];
  const int tid  = threadIdx.x;
  const int lane = tid & 63;
  const int wave = tid >> 6;
  const int c    = lane & 15;
  const int quad = lane >> 4;
  const int M0   = blockIdx.x * 32;
  const int jb   = blockIdx.y * (NSEQ / PV_GROUPS);
  const int je   = jb + NSEQ / PV_GROUPS;
  const int D0   = wave * 64;
  const int wmt  = wave >> 1;           // staging tile owned by this wave
  const int wks  = wave & 1;
  const int nq   = tid >> 3;            // normalize row 0..31
  const int ng   = tid & 7;             // normalize j-octet 0..7

  if (tid < 32) linv[tid] = 1.0f / lsum[M0 + tid];

  const size_t tq = (size_t)((M0 >> 4) + wmt);

  // prologue: stage chunk 0 into buf 0
  {
    const _Float16* src = P16F + (tq * 256 + (size_t)((jb >> 5) + wks)) * 512 + lane * 8;
    __builtin_amdgcn_global_load_lds((gptr_t)src, (lptr_t)&As[wave * 512], 16, 0, 0);
  }
  __syncthreads();                      // stage 0 complete + linv visible

  const float nscale = linv[nq];        // loop-invariant attn scale (row nq)
  // LDS offset of this thread's row-contiguous half8 within a buffer:
  const int nofs = ((nq >> 4) * 2 + (ng >> 2)) * 512 + ((ng & 3) * 16 + (nq & 15)) * 8;

  f32x4 acc[2][4] = {};
  int buf = 0;
  for (int j0 = jb; j0 < je; j0 += 64) {
    if (j0 + 64 < je) {
      const _Float16* src = P16F + (tq * 256 + (size_t)(((j0 + 64) >> 5) + wks)) * 512 + lane * 8;
      __builtin_amdgcn_global_load_lds((gptr_t)src,
          (lptr_t)&As[(buf ^ 1) * 2048 + wave * 512], 16, 0, 0);
    }

    // A-frags: conflict-free b128, all 4 tiles shared by all waves
    half8 af[2][2];
#pragma unroll
    for (int mt = 0; mt < 2; ++mt)
#pragma unroll
      for (int ks = 0; ks < 2; ++ks)
        af[mt][ks] = *(const half8*)&As[buf * 2048 + (mt*2 + ks) * 512 + lane * 8];

    // B-frags: VT rows (L2-hot, 4MB total)
    half8 bf[4][2];
#pragma unroll
    for (int ks = 0; ks < 2; ++ks)
#pragma unroll
      for (int nt = 0; nt < 4; ++nt)
        bf[nt][ks] = *(const half8*)&VT[(size_t)(D0 + nt*16 + c) * NSEQ + j0 + ks*32 + quad*8];

    // attn write: row-contiguous from LDS, full 256B sectors per wave
    {
      const half8 v = *(const half8*)&As[buf * 2048 + nofs];
      f32x4 w0, w1;
#pragma unroll
      for (int r = 0; r < 4; ++r) {
        w0[r] = (float)v[r]     * nscale;
        w1[r] = (float)v[r + 4] * nscale;
      }
      float* ar = attn + (size_t)(M0 + nq) * NSEQ + j0 + ng*8;
      *(f32x4*)ar       = w0;
      *(f32x4*)(ar + 4) = w1;
    }

    // PV MFMA (unnormalized accumulate)
#pragma unroll
    for (int ks = 0; ks < 2; ++ks)
#pragma unroll
      for (int mt = 0; mt < 2; ++mt)
#pragma unroll
        for (int nt = 0; nt < 4; ++nt)
          acc[mt][nt] = __builtin_amdgcn_mfma_f32_16x16x32_f16(af[mt][ks], bf[nt][ks], acc[mt][nt], 0, 0, 0);

    __syncthreads();                    // drains staging vmcnt; protects buf reuse
    buf ^= 1;
  }

  // epilogue: scale by 1/lsum, accumulate into cntx
#pragma unroll
  for (int mt = 0; mt < 2; ++mt)
#pragma unroll
    for (int r = 0; r < 4; ++r) {
      const float s = linv[mt*16 + quad*4 + r];
#pragma unroll
      for (int nt = 0; nt < 4; ++nt)
        atomicAdd(&cntx[(size_t)(M0 + mt*16 + quad*4 + r) * D_MODEL + D0 + nt*16 + c],
                  acc[mt][nt][r] * s);
    }
}

// ---------------------------------------------------------------------------
// k3 fallback (small ws): in-place f32 normalize + PV, unchanged semantics.
// ---------------------------------------------------------------------------
__global__ __launch_bounds__(256) void pv_kernel_f32(
    const float* __restrict__ Pin, float* __restrict__ attn,
    const float* __restrict__ lsum, const _Float16* __restrict__ VT,
    float* __restrict__ cntx)
{
  __shared__ float linv[32];
  const int tid  = threadIdx.x;
  const int lane = tid & 63;
  const int wave = tid >> 6;
  const int c    = lane & 15;
  const int quad = lane >> 4;
  const int M0   = blockIdx.x * 32;
  const int jb   = blockIdx.y * (NSEQ / PV_GROUPS);
  const int je   = jb + NSEQ / PV_GROUPS;
  const int D0   = wave * 64;
  const int nr   = tid >> 3;
  const int ncol = (tid & 7) * 8;

  if (tid < 32) linv[tid] = 1.0f / lsum[M0 + tid];
  __syncthreads();
  const float nscale = linv[nr];

  f32x4 acc[2][4] = {};
  for (int j0 = jb; j0 < je; j0 += 64) {
    const float* pr = Pin + (size_t)(M0 + nr) * NSEQ + j0 + ncol;
    f32x4 np0 = *(const f32x4*)pr;
    f32x4 np1 = *(const f32x4*)(pr + 4);

    half8 af[2][2], bf[4][2];
#pragma unroll
    for (int h = 0; h < 2; ++h) {
#pragma unroll
      for (int mt = 0; mt < 2; ++mt) {
        const float* pa = Pin + (size_t)(M0 + mt*16 + c) * NSEQ + j0 + h*32 + quad*8;
        af[mt][h] = cvt8(*(const f32x4*)pa, *(const f32x4*)(pa + 4));
      }
#pragma unroll
      for (int nt = 0; nt < 4; ++nt)
        bf[nt][h] = *(const half8*)&VT[(size_t)(D0 + nt*16 + c) * NSEQ + j0 + h*32 + quad*8];
    }

    __syncthreads();   // all reads of this tile before in-place writes

    float* ar = attn + (size_t)(M0 + nr) * NSEQ + j0 + ncol;
    *(f32x4*)ar       = np0 * nscale;
    *(f32x4*)(ar + 4) = np1 * nscale;

#pragma unroll
    for (int h = 0; h < 2; ++h)
#pragma unroll
      for (int mt = 0; mt < 2; ++mt)
#pragma unroll
        for (int nt = 0; nt < 4; ++nt)
          acc[mt][nt] = __builtin_amdgcn_mfma_f32_16x16x32_f16(af[mt][h], bf[nt][h], acc[mt][nt], 0, 0, 0);
  }

#pragma unroll
  for (int mt = 0; mt < 2; ++mt)
#pragma unroll
    for (int r = 0; r < 4; ++r) {
      const float s = linv[mt*16 + quad*4 + r];
#pragma unroll
      for (int nt = 0; nt < 4; ++nt)
        atomicAdd(&cntx[(size_t)(M0 + mt*16 + quad*4 + r) * D_MODEL + D0 + nt*16 + c],
                  acc[mt][nt][r] * s);
    }
}

// ---------------------------------------------------------------------------
extern "C" void kernel_launch(void* const* d_in, const int* in_sizes, int n_in,
                              void* d_out, int out_size, void* d_ws, size_t ws_size,
                              hipStream_t stream)
{
  const float* x  = (const float*)d_in[0];
  const float* Wq = (const float*)d_in[1];
  const float* Wk = (const float*)d_in[2];
  const float* Wv = (const float*)d_in[3];

  float* cntx = (float*)d_out;                         // [8192 x 256]
  float* attn = cntx + (size_t)NSEQ * D_MODEL;         // [8192 x 8192]

  // ws layout: QK16 (8MB) | VT (4MB) | lsum (32KB) | P16F (128MB, if room)
  _Float16* QK16 = (_Float16*)d_ws;
  _Float16* VT   = QK16 + (size_t)NSEQ * 512;
  float*    lsum = (float*)(VT + (size_t)D_MODEL * NSEQ);
  _Float16* P16F = (_Float16*)(lsum + NSEQ);

  const size_t base_bytes = (size_t)NSEQ*512*2 + (size_t)D_MODEL*NSEQ*2 + (size_t)NSEQ*4;
  const bool big_ws = ws_size >= base_bytes + (size_t)NSEQ * NSEQ * 2;

  hipMemsetAsync(cntx, 0, sizeof(float) * (size_t)NSEQ * D_MODEL, stream);
  hipMemsetAsync(lsum, 0, sizeof(float) * NSEQ, stream);

  qkv_kernel<<<dim3(128, 12), 64, 0, stream>>>(x, Wq, Wk, Wv, QK16, VT);

  if (big_ws) {
    score_kernel<true><<<dim3(64, 64), 256, 0, stream>>>(QK16, (void*)P16F, lsum);
    pv_kernel_p16<<<dim3(NSEQ/32, PV_GROUPS), 256, 0, stream>>>(P16F, attn, lsum, VT, cntx);
  } else {
    score_kernel<false><<<dim3(64, 64), 256, 0, stream>>>(QK16, (void*)attn, lsum);
    pv_kernel_f32<<<dim3(NSEQ/32, PV_GROUPS), 256, 0, stream>>>(attn, attn, lsum, VT, cntx);
  }
}